// Round 8
// baseline (545.678 us; speedup 1.0000x reference)
//
#include <hip/hip_runtime.h>
#include <hip/hip_bf16.h>

#define NCELL 64
#define CIN 8
#define EE 4
#define DD 4
#define HH 256
#define WW 256

#define EBH 16
#define NBH 16
#define NBANDS_E (HH / EBH)   // 16
#define NBANDS_N (HH / NBH)   // 16
#define NSTRIP 5              // 5 strips x 60 payload cols

#define COMP(v,i) ((i)==0?(v).x:(i)==1?(v).y:(i)==2?(v).z:(v).w)

__device__ __forceinline__ float4 f4z() { return make_float4(0.f, 0.f, 0.f, 0.f); }
__device__ __forceinline__ float silu1(float v) { return v / (1.0f + __expf(-v)); }
__device__ __forceinline__ float4 silu4(float4 v) {
    return make_float4(silu1(v.x), silu1(v.y), silu1(v.z), silu1(v.w));
}
__device__ __forceinline__ float4 shfL(float4 v) {   // value from lane-1
    return make_float4(__shfl_up(v.x, 1), __shfl_up(v.y, 1),
                       __shfl_up(v.z, 1), __shfl_up(v.w, 1));
}
__device__ __forceinline__ float4 shfR(float4 v) {   // value from lane+1
    return make_float4(__shfl_down(v.x, 1), __shfl_down(v.y, 1),
                       __shfl_down(v.z, 1), __shfl_down(v.w, 1));
}
__device__ __forceinline__ void fma4s(float4& a, float s, const float* __restrict__ w,
                                      int ostride, int idx) {
    a.x = fmaf(s, w[0 * ostride + idx], a.x);
    a.y = fmaf(s, w[1 * ostride + idx], a.y);
    a.z = fmaf(s, w[2 * ostride + idx], a.z);
    a.w = fmaf(s, w[3 * ostride + idx], a.w);
}

// contribution of one input row (cols x-1,x,x+1; 4 packed channels) with vertical
// role dy to one output row's 4-channel accumulator.
__device__ __forceinline__ void contrib3(float4 Lv, float4 Cv, float4 Rv,
                                         const float* __restrict__ w, int ostride,
                                         int ibase, int dy, float4& acc) {
#pragma unroll
    for (int ci = 0; ci < 4; ++ci) {
        const int idx = (ibase + ci) * 9 + dy * 3;
        fma4s(acc, COMP(Lv, ci), w, ostride, idx + 0);
        fma4s(acc, COMP(Cv, ci), w, ostride, idx + 1);
        fma4s(acc, COMP(Rv, ci), w, ostride, idx + 2);
    }
}

// ---------------- edge pass: one wave per (band, strip, cell) ----------------
__global__ __launch_bounds__(256) void edge_kernel(
    const float* __restrict__ x,
    const float* __restrict__ w_down, const float* __restrict__ b_down,
    const float* __restrict__ w_e1, const float* __restrict__ b_e1,
    const float* __restrict__ w_e2, const float* __restrict__ b_e2,
    float4* __restrict__ P)   // per-cell partials: P[n*65536 + y*256 + x]
{
    const int lane = threadIdx.x & 63;
    const int wv = threadIdx.x >> 6;
    const int y0 = blockIdx.x * EBH;
    const int s = blockIdx.y;
    const int n = blockIdx.z * 4 + wv;
    const int cx = s * 60 + lane - 2;
    const bool colok = (unsigned)cx < (unsigned)WW;
    const bool payload = (lane >= 2) && (lane < 62) && colok;
    const float* __restrict__ xn = x + (size_t)n * CIN * HH * WW;

    const float4 bdn = make_float4(b_down[0], b_down[1], b_down[2], b_down[3]);
    const float4 be1 = make_float4(b_e1[0], b_e1[1], b_e1[2], b_e1[3]);
    const float4 be2 = make_float4(b_e2[0], b_e2[1], b_e2[2], b_e2[3]);

    float4 hacc_a = f4z(), hacc_b = f4z();   // h1 partial accs (rows zr-1, zr)
    float4 oacc_a = f4z(), oacc_b = f4z();   // h2 partial accs

    for (int k = 0; k < EBH + 4; ++k) {
        const int zr = y0 - 2 + k;

        // ---- stage z(zr) = 1x1 down conv ----
        float4 zn = f4z();
        if ((unsigned)zr < (unsigned)HH && colok) {
            zn = bdn;
#pragma unroll
            for (int i = 0; i < CIN; ++i) {
                const float xv = xn[((size_t)i * HH + zr) * WW + cx];
                zn.x = fmaf(xv, w_down[0 * CIN + i], zn.x);
                zn.y = fmaf(xv, w_down[1 * CIN + i], zn.y);
                zn.z = fmaf(xv, w_down[2 * CIN + i], zn.z);
                zn.w = fmaf(xv, w_down[3 * CIN + i], zn.w);
            }
        }
        const float4 zL = shfL(zn), zR = shfR(zn);

        // ---- scatter z contributions into h1 accs ----
        float4 hacc_c = be1;                       // init row zr+1 (dy=0)
        contrib3(zL, zn, zR, w_e1, 36, 0, 0, hacc_c);
        contrib3(zL, zn, zR, w_e1, 36, 0, 1, hacc_b);
        contrib3(zL, zn, zR, w_e1, 36, 0, 2, hacc_a);

        // ---- complete h1 row hr = zr-1, scatter into h2 accs ----
        if (k >= 2) {
            const int hr = zr - 1;
            const float4 hn = ((unsigned)hr < (unsigned)HH && colok) ? silu4(hacc_a) : f4z();
            const float4 hL = shfL(hn), hR = shfR(hn);
            float4 oacc_c = be2;                   // init row hr+1 (dy=0)
            contrib3(hL, hn, hR, w_e2, 36, 0, 0, oacc_c);
            contrib3(hL, hn, hR, w_e2, 36, 0, 1, oacc_b);
            contrib3(hL, hn, hR, w_e2, 36, 0, 2, oacc_a);

            // ---- complete h2 row orow = hr-1 = zr-2, write partial ----
            if (k >= 4 && payload) {
                const int orow = zr - 2;
                P[(size_t)n * (HH * WW) + orow * WW + cx] = silu4(oacc_a);
            }
            oacc_a = oacc_b; oacc_b = oacc_c;
        }
        hacc_a = hacc_b; hacc_b = hacc_c;
    }
}

// ---------------- reduce over cells: A = sum_n P[n] ----------------
__global__ __launch_bounds__(256) void reduce_kernel(
    const float4* __restrict__ P, float4* __restrict__ A4)
{
    __shared__ float4 buf[256];
    const int tid = threadIdx.x;
    const int pix = blockIdx.x * 64 + (tid & 63);
    const int c0 = (tid >> 6) * 16;           // 16-cell chunk per thread
    float4 a = f4z(), b = f4z();
#pragma unroll
    for (int j = 0; j < 16; j += 2) {
        const float4 v0 = P[(size_t)(c0 + j + 0) * (HH * WW) + pix];
        const float4 v1 = P[(size_t)(c0 + j + 1) * (HH * WW) + pix];
        a.x += v0.x; a.y += v0.y; a.z += v0.z; a.w += v0.w;
        b.x += v1.x; b.y += v1.y; b.z += v1.z; b.w += v1.w;
    }
    buf[tid] = make_float4(a.x + b.x, a.y + b.y, a.z + b.z, a.w + b.w);
    __syncthreads();
    if (tid < 64) {
        const float4 p0 = buf[tid], p1 = buf[tid + 64], p2 = buf[tid + 128], p3 = buf[tid + 192];
        A4[blockIdx.x * 64 + tid] =
            make_float4(p0.x + p1.x + p2.x + p3.x, p0.y + p1.y + p2.y + p3.y,
                        p0.z + p1.z + p2.z + p3.z, p0.w + p1.w + p2.w + p3.w);
    }
}

// ---------------- node pass: one wave per (band, strip, cell) ----------------
__global__ __launch_bounds__(256) void node_kernel(
    const float* __restrict__ x, const float* __restrict__ A,
    const float* __restrict__ w_up, const float* __restrict__ b_up,
    const float* __restrict__ w_n1, const float* __restrict__ b_n1,
    const float* __restrict__ w_n2, const float* __restrict__ b_n2,
    const float* __restrict__ w_r, const float* __restrict__ b_r,
    float* __restrict__ out)
{
    const int lane = threadIdx.x & 63;
    const int wv = threadIdx.x >> 6;
    const int y0 = blockIdx.x * NBH;
    const int s = blockIdx.y;
    const int n = blockIdx.z * 4 + wv;
    const int cx = s * 60 + lane - 2;
    const bool colok = (unsigned)cx < (unsigned)WW;
    const bool payload = (lane >= 2) && (lane < 62) && colok;
    const float* __restrict__ xn = x + (size_t)n * CIN * HH * WW;
    const float4* __restrict__ A4 = reinterpret_cast<const float4*>(A);

    const float4 bup = make_float4(b_up[0], b_up[1], b_up[2], b_up[3]);
    const float4 bn1 = make_float4(b_n1[0], b_n1[1], b_n1[2], b_n1[3]);
    const float4 bn2r = make_float4(b_n2[0] + b_r[0], b_n2[1] + b_r[1],
                                    b_n2[2] + b_r[2], b_n2[3] + b_r[3]);

    float4 yacc_a = f4z(), yacc_b = f4z();   // y1 partial accs
    float4 oacc_a = f4z(), oacc_b = f4z();   // out partial accs

    for (int k = 0; k < NBH + 4; ++k) {
        const int zr = y0 - 2 + k;

        // ---- stage S(zr) = [x(2 groups) || up(A)] ----
        float4 S0 = f4z(), S1 = f4z(), S2 = f4z();
        if ((unsigned)zr < (unsigned)HH && colok) {
            float xv[CIN];
#pragma unroll
            for (int i = 0; i < CIN; ++i) xv[i] = xn[((size_t)i * HH + zr) * WW + cx];
            S0 = make_float4(xv[0], xv[1], xv[2], xv[3]);
            S1 = make_float4(xv[4], xv[5], xv[6], xv[7]);
            const float4 a4 = A4[zr * WW + cx];
            S2 = bup;
#pragma unroll
            for (int e = 0; e < 4; ++e) {
                const float av = COMP(a4, e);
                S2.x = fmaf(av, w_up[0 * EE + e], S2.x);
                S2.y = fmaf(av, w_up[1 * EE + e], S2.y);
                S2.z = fmaf(av, w_up[2 * EE + e], S2.z);
                S2.w = fmaf(av, w_up[3 * EE + e], S2.w);
            }
        }
        const float4 L0 = shfL(S0), R0 = shfR(S0);
        const float4 L1 = shfL(S1), R1 = shfR(S1);
        const float4 L2 = shfL(S2), R2 = shfR(S2);

        // ---- scatter S contributions into y1 accs (12ch -> 4ch) ----
        float4 yacc_c = bn1;                      // init row zr+1 (dy=0)
        contrib3(L0, S0, R0, w_n1, 108, 0, 0, yacc_c);
        contrib3(L1, S1, R1, w_n1, 108, 4, 0, yacc_c);
        contrib3(L2, S2, R2, w_n1, 108, 8, 0, yacc_c);
        contrib3(L0, S0, R0, w_n1, 108, 0, 1, yacc_b);
        contrib3(L1, S1, R1, w_n1, 108, 4, 1, yacc_b);
        contrib3(L2, S2, R2, w_n1, 108, 8, 1, yacc_b);
        contrib3(L0, S0, R0, w_n1, 108, 0, 2, yacc_a);
        contrib3(L1, S1, R1, w_n1, 108, 4, 2, yacc_a);
        contrib3(L2, S2, R2, w_n1, 108, 8, 2, yacc_a);

        // ---- complete y1 row hr = zr-1, scatter into out accs ----
        if (k >= 2) {
            const int hr = zr - 1;
            const float4 yn = ((unsigned)hr < (unsigned)HH && colok) ? silu4(yacc_a) : f4z();
            const float4 yL = shfL(yn), yR = shfR(yn);

            // init out-row hr+1 = zr: bias + residual 1x1 on x row zr (= S0,S1)
            float4 oacc_c = bn2r;
#pragma unroll
            for (int ci = 0; ci < 4; ++ci) {
                fma4s(oacc_c, COMP(S0, ci), w_r, CIN, ci);
                fma4s(oacc_c, COMP(S1, ci), w_r, CIN, 4 + ci);
            }
            contrib3(yL, yn, yR, w_n2, 36, 0, 0, oacc_c);
            contrib3(yL, yn, yR, w_n2, 36, 0, 1, oacc_b);
            contrib3(yL, yn, yR, w_n2, 36, 0, 2, oacc_a);

            // ---- complete out row orow = zr-2, store ----
            if (k >= 4 && payload) {
                const int orow = zr - 2;
                out[(((size_t)n * DD + 0) * HH + orow) * WW + cx] = oacc_a.x;
                out[(((size_t)n * DD + 1) * HH + orow) * WW + cx] = oacc_a.y;
                out[(((size_t)n * DD + 2) * HH + orow) * WW + cx] = oacc_a.z;
                out[(((size_t)n * DD + 3) * HH + orow) * WW + cx] = oacc_a.w;
            }
            oacc_a = oacc_b; oacc_b = oacc_c;
        }
        yacc_a = yacc_b; yacc_b = yacc_c;
    }
}

extern "C" void kernel_launch(void* const* d_in, const int* in_sizes, int n_in,
                              void* d_out, int out_size, void* d_ws, size_t ws_size,
                              hipStream_t stream) {
    const float* x      = (const float*)d_in[0];
    const float* w_down = (const float*)d_in[1];
    const float* b_down = (const float*)d_in[2];
    const float* w_e1   = (const float*)d_in[3];
    const float* b_e1   = (const float*)d_in[4];
    const float* w_e2   = (const float*)d_in[5];
    const float* b_e2   = (const float*)d_in[6];
    const float* w_up   = (const float*)d_in[7];
    const float* b_up   = (const float*)d_in[8];
    const float* w_n1   = (const float*)d_in[9];
    const float* b_n1   = (const float*)d_in[10];
    const float* w_n2   = (const float*)d_in[11];
    const float* b_n2   = (const float*)d_in[12];
    const float* w_r    = (const float*)d_in[13];
    const float* b_r    = (const float*)d_in[14];
    float* out = (float*)d_out;

    // Per-cell edge partials exactly fill d_out; node overwrites d_out afterwards.
    float4* P = (float4*)d_out;
    float* A  = (float*)d_ws;   // 1 MiB pixel-major aggregate

    edge_kernel<<<dim3(NBANDS_E, NSTRIP, NCELL / 4), dim3(256), 0, stream>>>(
        x, w_down, b_down, w_e1, b_e1, w_e2, b_e2, P);

    reduce_kernel<<<dim3(HH * WW / 64), dim3(256), 0, stream>>>(P, (float4*)A);

    node_kernel<<<dim3(NBANDS_N, NSTRIP, NCELL / 4), dim3(256), 0, stream>>>(
        x, A, w_up, b_up, w_n1, b_n1, w_n2, b_n2, w_r, b_r, out);
}